// Round 17
// baseline (89.601 us; speedup 1.0000x reference)
//
#include <hip/hip_runtime.h>
#include <stdint.h>

typedef __attribute__((ext_vector_type(8))) short short8;
typedef __attribute__((ext_vector_type(4))) float f32x4;
typedef __attribute__((ext_vector_type(16))) float f32x16;
typedef __attribute__((ext_vector_type(4))) int i32x4;
typedef __attribute__((ext_vector_type(2))) int i32x2;

#define MFMA16(a, b, c) __builtin_amdgcn_mfma_f32_16x16x32_bf16((a), (b), (c), 0, 0, 0)
#define MFMA32(a, b, c) __builtin_amdgcn_mfma_f32_32x32x16_bf16((a), (b), (c), 0, 0, 0)

typedef __attribute__((address_space(1))) const void GVoid;
typedef __attribute__((address_space(3))) void LVoid;
#define GLDS16(g, l) __builtin_amdgcn_global_load_lds((GVoid*)(g), (LVoid*)(l), 16, 0, 0)

#define L2E 1.4426950408889634f

__device__ __forceinline__ unsigned short f2bf(float f) {
  unsigned int u = __builtin_bit_cast(unsigned int, f);
  u += 0x7fffu + ((u >> 16) & 1u);   // RNE (finite values only)
  return (unsigned short)(u >> 16);
}
__device__ __forceinline__ float bf2f(unsigned short u) {
  return __builtin_bit_cast(float, (unsigned int)u << 16);
}

// raw v_exp_f32: args always <= 0; flush-to-zero is the wanted semantics.
__device__ __forceinline__ float fexp2(float x) {
  return __builtin_amdgcn_exp2f(x);
}

// permlane32_swap via builtin: two simultaneously-live results -> distinct regs
// guaranteed (inline-asm "+v","+v" self-swap was R3's bug).
__device__ __forceinline__ i32x2 pls(int a, int b) {
  return __builtin_amdgcn_permlane32_swap(a, b, false, false);
}
__device__ __forceinline__ float fasf(int x) { return __builtin_bit_cast(float, x); }
__device__ __forceinline__ int iasi(float x) { return __builtin_bit_cast(int, x); }

__device__ __forceinline__ int cvtpk(float lo, float hi) {
  int d;
  asm("v_cvt_pk_bf16_f32 %0, %1, %2" : "=v"(d) : "v"(lo), "v"(hi));
  return d;
}

// ---------------------------------------------------------------------------
// Kernel 1: Q/K/V projections (unchanged from R16).
// ---------------------------------------------------------------------------
__global__ __launch_bounds__(256) void k_proj(
    const float* __restrict__ x,
    const float* __restrict__ Wq, const float* __restrict__ bq,
    const float* __restrict__ Wk, const float* __restrict__ bk,
    const float* __restrict__ Wv, const float* __restrict__ bv,
    const float* __restrict__ Wo,
    unsigned short* __restrict__ Q2, unsigned short* __restrict__ K2,
    unsigned short* __restrict__ V2, unsigned short* __restrict__ Wo2)
{
  __shared__ __align__(16) unsigned short wt[128 * 128];  // swizzled W^T, 32KB
  __shared__ __align__(16) unsigned short st[64 * 136];   // store-stage, 17KB
  const int tid  = threadIdx.x;
  const int lane = tid & 63;
  const int wid  = tid >> 6;
  const int l15  = lane & 15;
  const int g    = lane >> 4;
  const int wI   = blockIdx.x >> 8;      // 0=Q, 1=K, 2=V
  const int blk  = blockIdx.x & 255;
  const int r0   = blk * 64 + wid * 16;

  if (blockIdx.x == 0) {
    for (int e = tid; e < 16384; e += 256) {
      int j = e & 7, ln = (e >> 3) & 63, kt = (e >> 9) & 7, dt = e >> 12;
      int h = kt * 16 + (ln >> 5) * 8 + j, oc = dt * 32 + (ln & 31);
      Wo2[e] = f2bf(Wo[h * 128 + oc]);
    }
  }

  short8 af[4];
  {
    const float* xp = x + (r0 + l15) * 128 + g * 8;
#pragma unroll
    for (int kt = 0; kt < 4; ++kt) {
      float4 v0 = *(const float4*)(xp + kt * 32);
      float4 v1 = *(const float4*)(xp + kt * 32 + 4);
      short8 a;
      a[0] = (short)f2bf(v0.x); a[1] = (short)f2bf(v0.y);
      a[2] = (short)f2bf(v0.z); a[3] = (short)f2bf(v0.w);
      a[4] = (short)f2bf(v1.x); a[5] = (short)f2bf(v1.y);
      a[6] = (short)f2bf(v1.z); a[7] = (short)f2bf(v1.w);
      af[kt] = a;
    }
  }

  const float* W  = (wI == 0) ? Wq : (wI == 1) ? Wk : Wv;
  const float* bv_ = (wI == 0) ? bq : (wI == 1) ? bk : bv;

  for (int i = 0; i < 64; ++i) {
    int idx = i * 256 + tid;
    int k = idx >> 7, n = idx & 127;
    int cs = (k >> 3) ^ (n & 7);
    wt[n * 128 + cs * 8 + (k & 7)] = f2bf(W[idx]);
  }
  __syncthreads();

  float bias[8];
#pragma unroll
  for (int nt = 0; nt < 8; ++nt) bias[nt] = bv_[nt * 16 + l15];

  f32x4 acc[8];
#pragma unroll
  for (int nt = 0; nt < 8; ++nt) acc[nt] = (f32x4){0.f, 0.f, 0.f, 0.f};

#pragma unroll
  for (int nt = 0; nt < 8; ++nt) {
    const int n = nt * 16 + l15;
#pragma unroll
    for (int ks = 0; ks < 4; ++ks) {
      int cs = (ks * 4 + g) ^ (n & 7);
      short8 bf = *(const short8*)&wt[n * 128 + cs * 8];
      acc[nt] = MFMA16(af[ks], bf, acc[nt]);
    }
  }

  if (wI < 2) {
    const float sc = (wI == 0) ? 0.08838834764831845f : 1.0f;  // 1/sqrt(128)
#pragma unroll
    for (int nt = 0; nt < 8; ++nt) {
      int col = nt * 16 + l15;
#pragma unroll
      for (int r = 0; r < 4; ++r)
        st[(wid * 16 + g * 4 + r) * 136 + col] = f2bf((acc[nt][r] + bias[nt]) * sc);
    }
    __syncthreads();
    unsigned short* Og = (wI == 0) ? Q2 : K2;
#pragma unroll
    for (int c4 = 0; c4 < 4; ++c4) {
      int c = c4 * 256 + tid;
      int T = c >> 9, cc = c & 511;
      int kt = cc >> 6, hib = (cc >> 5) & 1, s32 = cc & 31;
      int m0 = blk * 64 + T * 32;
      int bb = m0 >> 12, tile = (m0 & 4095) >> 5;
      short8 v = *(const short8*)&st[(T * 32 + s32) * 136 + kt * 16 + hib * 8];
      *(short8*)&Og[(size_t)(bb * 128 + tile) * 4096 + cc * 8] = v;
    }
  } else {
#pragma unroll
    for (int nt = 0; nt < 8; ++nt) {
      int col = nt * 16 + l15;
      int m0 = r0 + g * 4;
      int bb = m0 >> 12, srow = m0 & 4095;
      int idx = (bb * 128 + (srow >> 5)) * 4096 + ((srow >> 4) & 1) * 2048 +
                (col >> 5) * 512 + ((srow >> 3) & 1) * 256 + (col & 31) * 8 +
                (srow & 7);
      ushort4 pk;
      pk.x = f2bf(acc[nt][0] + bias[nt]);
      pk.y = f2bf(acc[nt][1] + bias[nt]);
      pk.z = f2bf(acc[nt][2] + bias[nt]);
      pk.w = f2bf(acc[nt][3] + bias[nt]);
      *(ushort4*)&V2[idx] = pk;
    }
  }
}

// ---------------------------------------------------------------------------
// Kernel 2: flash attention partials. KVBLK=32 this round: 16KB staged tile
// (K 8KB + V 8KB), double-buffered = 33.8KB LDS/block -> FOUR blocks/CU
// (4 waves/SIMD, 4 independent barrier domains; was 2 at KVBLK=64).
// Grid 512 = (4 b) x (32 q-supertiles of 128 rows) x (4 KV quarters);
// 256 thr = 4 waves x 32 q-rows. 32 iters; 4 GLDS16/thread/iter, counted
// vmcnt(4); two raw s_barriers per iter. launch_bounds(256,4) caps VGPR at
// 128 (natural ~80 -> no spill; R12's cap-64 spill lesson).
// ---------------------------------------------------------------------------
__global__ __launch_bounds__(256, 4) void k_attn(
    const unsigned short* __restrict__ Q2,
    const unsigned short* __restrict__ K2,
    const unsigned short* __restrict__ V2,
    unsigned short* __restrict__ PA,
    float2* __restrict__ ML2)
{
  __shared__ __align__(16) char smem[33792];   // 2 x 16KB bufs + 1KB RBUF
  const int tid = threadIdx.x, lane = tid & 63, wid = tid >> 6;   // wid 0..3
  const int rr = lane & 31, hi = lane >> 5;
  // XCD-aware: batch b pinned to XCD pair {2b,2b+1}
  const int p = blockIdx.x;
  const int b = (p & 7) >> 1;
  const int idx = ((p >> 3) << 1) | (p & 1);   // 0..127
  const int qst = idx >> 2, kvq = idx & 3;     // qst 0..31
  const int q0tile = qst * 4 + wid;            // 32q-tile index 0..127

  // Q fragments (pre-scaled): 8 coalesced 1KB loads
  short8 qf[8];
  {
    const unsigned short* qp = Q2 + (size_t)(b * 128 + q0tile) * 4096 + lane * 8;
#pragma unroll
    for (int kt = 0; kt < 8; ++kt) qf[kt] = *(const short8*)(qp + kt * 512);
  }

  // staging bases: one 32-row K tile (8KB) + one V tile (8KB) per iter
  const unsigned short* kbase = K2 + (size_t)(b * 128 + kvq * 32) * 4096 + tid * 8;
  const unsigned short* vbase = V2 + (size_t)(b * 128 + kvq * 32) * 4096 + tid * 8;

  char* const rbuf = smem + 32768 + wid * 128;

  // prologue: stage tile 0 into buf 0
  GLDS16(kbase,        smem + tid * 16);
  GLDS16(kbase + 2048, smem + 4096 + tid * 16);
  GLDS16(vbase,        smem + 8192 + tid * 16);
  GLDS16(vbase + 2048, smem + 12288 + tid * 16);

  f32x16 O[4];
#pragma unroll
  for (int dt = 0; dt < 4; ++dt)
#pragma unroll
    for (int j = 0; j < 16; ++j) O[dt][j] = 0.f;
  f32x16 zc;
#pragma unroll
  for (int j = 0; j < 16; ++j) zc[j] = 0.f;
  float mS = -3.0e38f, lS = 0.f;

  for (int t = 0; t < 32; ++t) {
    char* const b0 = smem + (t & 1) * 16384;
    if (t < 31) {
      char* const bn = smem + ((t + 1) & 1) * 16384;
      const size_t adv = (size_t)(t + 1) * 4096;
      GLDS16(kbase + adv,        bn + tid * 16);
      GLDS16(kbase + adv + 2048, bn + 4096 + tid * 16);
      GLDS16(vbase + adv,        bn + 8192 + tid * 16);
      GLDS16(vbase + adv + 2048, bn + 12288 + tid * 16);
      asm volatile("s_waitcnt vmcnt(4)" ::: "memory");  // tile-t slices landed
    } else {
      asm volatile("s_waitcnt vmcnt(0)" ::: "memory");
    }
    __builtin_amdgcn_s_barrier();                       // ALL tile-t slices in LDS
    __builtin_amdgcn_sched_barrier(0);

    // ---- QK^T swapped: D[kv=regs][q=lane&31] ----
    f32x16 sT;
    __builtin_amdgcn_s_setprio(1);
    {
      short8 kf[8];
#pragma unroll
      for (int kt = 0; kt < 8; ++kt)
        kf[kt] = *(const short8*)(b0 + kt * 1024 + lane * 16);
      sT = MFMA32(kf[0], qf[0], zc);
#pragma unroll
      for (int kt = 1; kt < 8; ++kt) sT = MFMA32(kf[kt], qf[kt], sT);
    }
    __builtin_amdgcn_s_setprio(0);

    // ---- online softmax over 32 kv; kv row of reg r = (r&3)+8*(r>>2)+4*hi --
    float pm = fmaxf(fmaxf(fmaxf(sT[0], sT[1]), fmaxf(sT[2], sT[3])),
                     fmaxf(fmaxf(sT[4], sT[5]), fmaxf(sT[6], sT[7])));
    pm = fmaxf(pm, fmaxf(fmaxf(fmaxf(sT[8], sT[9]), fmaxf(sT[10], sT[11])),
                         fmaxf(fmaxf(sT[12], sT[13]), fmaxf(sT[14], sT[15]))));
    { i32x2 r = pls(iasi(pm), iasi(pm)); pm = fmaxf(fasf(r[0]), fasf(r[1])); }

    if (!__all(pm - mS <= 8.0f)) {          // defer-max (THR=8)
      float mnew = fmaxf(mS, pm);
      float fsc = fexp2((mS - mnew) * L2E);
      mS = mnew;
      lS *= fsc;
      if (hi == 0) *(float*)(rbuf + rr * 4) = fsc;
      f32x4 fr[4];
#pragma unroll
      for (int i = 0; i < 4; ++i)
        fr[i] = *(const f32x4*)(rbuf + i * 32 + hi * 16);
#pragma unroll
      for (int dt = 0; dt < 4; ++dt)
#pragma unroll
        for (int i = 0; i < 4; ++i)
#pragma unroll
          for (int j = 0; j < 4; ++j) O[dt][i * 4 + j] *= fr[i][j];
    }

    const float mL = mS * L2E;
    float pv[16];
#pragma unroll
    for (int r = 0; r < 16; ++r) pv[r] = fexp2(sT[r] * L2E - mL);
    float s01 = (pv[0] + pv[1]) + (pv[2] + pv[3]);
    float s23 = (pv[4] + pv[5]) + (pv[6] + pv[7]);
    float s45 = (pv[8] + pv[9]) + (pv[10] + pv[11]);
    float s67 = (pv[12] + pv[13]) + (pv[14] + pv[15]);
    float ts = (s01 + s23) + (s45 + s67);
    { i32x2 r = pls(iasi(ts), iasi(ts)); ts = fasf(r[0]) + fasf(r[1]); }
    lS += ts;

    // ---- P -> PV A-fragments fully in registers (T12) ----
    short8 pa0, pa1;
    {
      int dw[8];
#pragma unroll
      for (int m = 0; m < 8; ++m) dw[m] = cvtpk(pv[2 * m], pv[2 * m + 1]);
      i32x2 ra = pls(dw[0], dw[2]);
      i32x2 rb = pls(dw[1], dw[3]);
      i32x2 rc = pls(dw[4], dw[6]);
      i32x2 rd = pls(dw[5], dw[7]);
      i32x4 w0 = {ra[0], rb[0], ra[1], rb[1]};
      i32x4 w1 = {rc[0], rd[0], rc[1], rd[1]};
      pa0 = __builtin_bit_cast(short8, w0);
      pa1 = __builtin_bit_cast(short8, w1);
    }

    // ---- PV: O[q][d] += P[q][kv32] * V[kv32][d] ----
    __builtin_amdgcn_s_setprio(1);
    {
      const char* vb = b0 + 8192;
      short8 vf[4];
#pragma unroll
      for (int dt = 0; dt < 4; ++dt)
        vf[dt] = *(const short8*)(vb + dt * 1024 + lane * 16);
#pragma unroll
      for (int dt = 0; dt < 4; ++dt) O[dt] = MFMA32(pa0, vf[dt], O[dt]);
#pragma unroll
      for (int dt = 0; dt < 4; ++dt)
        vf[dt] = *(const short8*)(vb + 4096 + dt * 1024 + lane * 16);
#pragma unroll
      for (int dt = 0; dt < 4; ++dt) O[dt] = MFMA32(pa1, vf[dt], O[dt]);
    }
    __builtin_amdgcn_s_setprio(0);

    // trailing barrier: all waves done reading b0 -> free for restage at t+1
    __builtin_amdgcn_s_barrier();
  }

  // ---- epilogue: write partial A-frag image + (m,l) ----
  unsigned short* pab = PA + ((size_t)(b * 4 + kvq) * 128 + q0tile) * 4096;
#pragma unroll
  for (int dt = 0; dt < 4; ++dt) {
    int kt = dt * 2 + (rr >> 4);
#pragma unroll
    for (int r = 0; r < 16; ++r) {
      int q = (r & 3) + 8 * (r >> 2) + 4 * hi;
      int e = kt * 512 + (((rr >> 3) & 1) * 32 + q) * 8 + (rr & 7);
      pab[e] = f2bf(O[dt][r]);
    }
  }
  if (hi == 0)
    ML2[(size_t)(b * 4 + kvq) * 4096 + q0tile * 32 + rr] = make_float2(mS, lS);
}

// ---------------------------------------------------------------------------
// Kernel 3: merge 4 KV-quarter partials + fused output projection
// (unchanged from R16; XCD-aware mapping matches k_attn's producers).
// ---------------------------------------------------------------------------
__global__ __launch_bounds__(256) void k_merge(
    const unsigned short* __restrict__ PA,
    const float2* __restrict__ ML2,
    const unsigned short* __restrict__ Wo2,
    const float* __restrict__ bo,
    float* __restrict__ out)
{
  const int tid = threadIdx.x, lane = tid & 63, w = tid >> 6;
  const int rr = lane & 31, hi = lane >> 5;
  const int p = blockIdx.x;
  const int b = (p & 7) >> 1;
  const int qt32 = ((p >> 3) << 1) | (p & 1);   // 0..127

  float mh[4], lh[4];
#pragma unroll
  for (int h = 0; h < 4; ++h) {
    float2 ml = ML2[(size_t)(b * 4 + h) * 4096 + qt32 * 32 + rr];
    mh[h] = ml.x; lh[h] = ml.y;
  }
  float M = fmaxf(fmaxf(mh[0], mh[1]), fmaxf(mh[2], mh[3]));
  float ch[4], L = 0.f;
#pragma unroll
  for (int h = 0; h < 4; ++h) { ch[h] = fexp2((mh[h] - M) * L2E); L += ch[h] * lh[h]; }
  float iL = 1.0f / L;
#pragma unroll
  for (int h = 0; h < 4; ++h) ch[h] *= iL;

  short8 attb[8];
#pragma unroll
  for (int kt = 0; kt < 8; ++kt) {
    float a[8];
#pragma unroll
    for (int j = 0; j < 8; ++j) a[j] = 0.f;
#pragma unroll
    for (int h = 0; h < 4; ++h) {
      short8 ph = *(const short8*)(PA + ((size_t)(b * 4 + h) * 128 + qt32) * 4096 +
                                   kt * 512 + lane * 8);
#pragma unroll
      for (int j = 0; j < 8; ++j)
        a[j] += ch[h] * bf2f((unsigned short)ph[j]);
    }
    i32x4 wv = {cvtpk(a[0], a[1]), cvtpk(a[2], a[3]),
                cvtpk(a[4], a[5]), cvtpk(a[6], a[7])};
    attb[kt] = __builtin_bit_cast(short8, wv);
  }

  short8 wof[8];
#pragma unroll
  for (int kt = 0; kt < 8; ++kt)
    wof[kt] = *(const short8*)(Wo2 + (w * 8 + kt) * 512 + lane * 8);

  f32x16 zc;
#pragma unroll
  for (int j = 0; j < 16; ++j) zc[j] = 0.f;
  f32x16 acc = MFMA32(attb[0], wof[0], zc);
#pragma unroll
  for (int kt = 1; kt < 8; ++kt) acc = MFMA32(attb[kt], wof[kt], acc);

  float bov = bo[w * 32 + rr];
  float* op = out + (size_t)(b * 4096 + qt32 * 32) * 128 + w * 32 + rr;
#pragma unroll
  for (int r = 0; r < 16; ++r) {
    int q = (r & 3) + 8 * (r >> 2) + 4 * hi;
    op[q * 128] = acc[r] + bov;
  }
}

// ---------------------------------------------------------------------------
extern "C" void kernel_launch(void* const* d_in, const int* in_sizes, int n_in,
                              void* d_out, int out_size, void* d_ws, size_t ws_size,
                              hipStream_t stream) {
  const float* x  = (const float*)d_in[0];
  const float* Wq = (const float*)d_in[1];
  const float* bq = (const float*)d_in[2];
  const float* Wk = (const float*)d_in[3];
  const float* bk = (const float*)d_in[4];
  const float* Wv = (const float*)d_in[5];
  const float* bv = (const float*)d_in[6];
  const float* Wo = (const float*)d_in[7];
  const float* bo = (const float*)d_in[8];

  const size_t NE = 4u * 4096u * 128u;       // 2M elems per tensor
  unsigned short* Q2  = (unsigned short*)d_ws;
  unsigned short* K2  = Q2 + NE;
  unsigned short* V2  = K2 + NE;
  unsigned short* Wo2 = V2 + NE;             // 16384 elems
  unsigned short* PA  = Wo2 + 16384;         // 16 * 128 * 4096 = 8M elems
  float2*         ML2 = (float2*)(PA + (size_t)16 * 128 * 4096);  // 64K float2

  k_proj<<<768, 256, 0, stream>>>(x, Wq, bq, Wk, bk, Wv, bv, Wo, Q2, K2, V2, Wo2);
  k_attn<<<512, 256, 0, stream>>>(Q2, K2, V2, PA, ML2);
  k_merge<<<512, 256, 0, stream>>>(PA, ML2, Wo2, bo, (float*)d_out);
}

// Round 18
// 83.602 us; speedup vs baseline: 1.0718x; 1.0718x over previous
//
#include <hip/hip_runtime.h>
#include <stdint.h>

typedef __attribute__((ext_vector_type(8))) short short8;
typedef __attribute__((ext_vector_type(4))) float f32x4;
typedef __attribute__((ext_vector_type(16))) float f32x16;
typedef __attribute__((ext_vector_type(4))) int i32x4;
typedef __attribute__((ext_vector_type(2))) int i32x2;

#define MFMA16(a, b, c) __builtin_amdgcn_mfma_f32_16x16x32_bf16((a), (b), (c), 0, 0, 0)
#define MFMA32(a, b, c) __builtin_amdgcn_mfma_f32_32x32x16_bf16((a), (b), (c), 0, 0, 0)

typedef __attribute__((address_space(1))) const void GVoid;
typedef __attribute__((address_space(3))) void LVoid;
#define GLDS16(g, l) __builtin_amdgcn_global_load_lds((GVoid*)(g), (LVoid*)(l), 16, 0, 0)

#define L2E 1.4426950408889634f

__device__ __forceinline__ unsigned short f2bf(float f) {
  unsigned int u = __builtin_bit_cast(unsigned int, f);
  u += 0x7fffu + ((u >> 16) & 1u);   // RNE (finite values only)
  return (unsigned short)(u >> 16);
}
__device__ __forceinline__ float bf2f(unsigned short u) {
  return __builtin_bit_cast(float, (unsigned int)u << 16);
}

// raw v_exp_f32: args always <= 0; flush-to-zero is the wanted semantics.
__device__ __forceinline__ float fexp2(float x) {
  return __builtin_amdgcn_exp2f(x);
}

// permlane32_swap via builtin: two simultaneously-live results -> distinct regs
// guaranteed (inline-asm "+v","+v" self-swap was R3's bug).
__device__ __forceinline__ i32x2 pls(int a, int b) {
  return __builtin_amdgcn_permlane32_swap(a, b, false, false);
}
__device__ __forceinline__ float fasf(int x) { return __builtin_bit_cast(float, x); }
__device__ __forceinline__ int iasi(float x) { return __builtin_bit_cast(int, x); }

__device__ __forceinline__ int cvtpk(float lo, float hi) {
  int d;
  asm("v_cvt_pk_bf16_f32 %0, %1, %2" : "=v"(d) : "v"(lo), "v"(hi));
  return d;
}

// ---------------------------------------------------------------------------
// Kernel 1: Q/K/V projections (unchanged from R16).
// ---------------------------------------------------------------------------
__global__ __launch_bounds__(256) void k_proj(
    const float* __restrict__ x,
    const float* __restrict__ Wq, const float* __restrict__ bq,
    const float* __restrict__ Wk, const float* __restrict__ bk,
    const float* __restrict__ Wv, const float* __restrict__ bv,
    const float* __restrict__ Wo,
    unsigned short* __restrict__ Q2, unsigned short* __restrict__ K2,
    unsigned short* __restrict__ V2, unsigned short* __restrict__ Wo2)
{
  __shared__ __align__(16) unsigned short wt[128 * 128];  // swizzled W^T, 32KB
  __shared__ __align__(16) unsigned short st[64 * 136];   // store-stage, 17KB
  const int tid  = threadIdx.x;
  const int lane = tid & 63;
  const int wid  = tid >> 6;
  const int l15  = lane & 15;
  const int g    = lane >> 4;
  const int wI   = blockIdx.x >> 8;      // 0=Q, 1=K, 2=V
  const int blk  = blockIdx.x & 255;
  const int r0   = blk * 64 + wid * 16;

  if (blockIdx.x == 0) {
    for (int e = tid; e < 16384; e += 256) {
      int j = e & 7, ln = (e >> 3) & 63, kt = (e >> 9) & 7, dt = e >> 12;
      int h = kt * 16 + (ln >> 5) * 8 + j, oc = dt * 32 + (ln & 31);
      Wo2[e] = f2bf(Wo[h * 128 + oc]);
    }
  }

  short8 af[4];
  {
    const float* xp = x + (r0 + l15) * 128 + g * 8;
#pragma unroll
    for (int kt = 0; kt < 4; ++kt) {
      float4 v0 = *(const float4*)(xp + kt * 32);
      float4 v1 = *(const float4*)(xp + kt * 32 + 4);
      short8 a;
      a[0] = (short)f2bf(v0.x); a[1] = (short)f2bf(v0.y);
      a[2] = (short)f2bf(v0.z); a[3] = (short)f2bf(v0.w);
      a[4] = (short)f2bf(v1.x); a[5] = (short)f2bf(v1.y);
      a[6] = (short)f2bf(v1.z); a[7] = (short)f2bf(v1.w);
      af[kt] = a;
    }
  }

  const float* W  = (wI == 0) ? Wq : (wI == 1) ? Wk : Wv;
  const float* bv_ = (wI == 0) ? bq : (wI == 1) ? bk : bv;

  for (int i = 0; i < 64; ++i) {
    int idx = i * 256 + tid;
    int k = idx >> 7, n = idx & 127;
    int cs = (k >> 3) ^ (n & 7);
    wt[n * 128 + cs * 8 + (k & 7)] = f2bf(W[idx]);
  }
  __syncthreads();

  float bias[8];
#pragma unroll
  for (int nt = 0; nt < 8; ++nt) bias[nt] = bv_[nt * 16 + l15];

  f32x4 acc[8];
#pragma unroll
  for (int nt = 0; nt < 8; ++nt) acc[nt] = (f32x4){0.f, 0.f, 0.f, 0.f};

#pragma unroll
  for (int nt = 0; nt < 8; ++nt) {
    const int n = nt * 16 + l15;
#pragma unroll
    for (int ks = 0; ks < 4; ++ks) {
      int cs = (ks * 4 + g) ^ (n & 7);
      short8 bf = *(const short8*)&wt[n * 128 + cs * 8];
      acc[nt] = MFMA16(af[ks], bf, acc[nt]);
    }
  }

  if (wI < 2) {
    const float sc = (wI == 0) ? 0.08838834764831845f : 1.0f;  // 1/sqrt(128)
#pragma unroll
    for (int nt = 0; nt < 8; ++nt) {
      int col = nt * 16 + l15;
#pragma unroll
      for (int r = 0; r < 4; ++r)
        st[(wid * 16 + g * 4 + r) * 136 + col] = f2bf((acc[nt][r] + bias[nt]) * sc);
    }
    __syncthreads();
    unsigned short* Og = (wI == 0) ? Q2 : K2;
#pragma unroll
    for (int c4 = 0; c4 < 4; ++c4) {
      int c = c4 * 256 + tid;
      int T = c >> 9, cc = c & 511;
      int kt = cc >> 6, hib = (cc >> 5) & 1, s32 = cc & 31;
      int m0 = blk * 64 + T * 32;
      int bb = m0 >> 12, tile = (m0 & 4095) >> 5;
      short8 v = *(const short8*)&st[(T * 32 + s32) * 136 + kt * 16 + hib * 8];
      *(short8*)&Og[(size_t)(bb * 128 + tile) * 4096 + cc * 8] = v;
    }
  } else {
#pragma unroll
    for (int nt = 0; nt < 8; ++nt) {
      int col = nt * 16 + l15;
      int m0 = r0 + g * 4;
      int bb = m0 >> 12, srow = m0 & 4095;
      int idx = (bb * 128 + (srow >> 5)) * 4096 + ((srow >> 4) & 1) * 2048 +
                (col >> 5) * 512 + ((srow >> 3) & 1) * 256 + (col & 31) * 8 +
                (srow & 7);
      ushort4 pk;
      pk.x = f2bf(acc[nt][0] + bias[nt]);
      pk.y = f2bf(acc[nt][1] + bias[nt]);
      pk.z = f2bf(acc[nt][2] + bias[nt]);
      pk.w = f2bf(acc[nt][3] + bias[nt]);
      *(ushort4*)&V2[idx] = pk;
    }
  }
}

// ---------------------------------------------------------------------------
// Kernel 2: flash attention partials, templated on KV split NH (8 or 4).
// Grid 128*NH = (4 b) x (32 q-supertiles of 128 rows) x (NH KV slices);
// 256 thr = 4 waves x 32 q-rows. KVBLK=32, ITERS = 4096/NH/32.
// NH=8: grid 1024 -> FOUR blocks/CU (33.8KB LDS each) = 16 waves/CU —
//   this is the TLP lever (R13/R17 lesson: blocks/CU = grid/256, full stop).
// launch_bounds(256,2): cap 256 VGPR >> natural ~80 -> NO spill (R12/R17
//   lesson: an aggressive min-waves bound spills and loses 1.3-1.7x).
// Double-buffered 16KB K+V tile, 4 GLDS16/thread/iter, counted vmcnt(4),
// two raw s_barriers per iter.
// ---------------------------------------------------------------------------
template <int NH>
__global__ __launch_bounds__(256, 2) void k_attn(
    const unsigned short* __restrict__ Q2,
    const unsigned short* __restrict__ K2,
    const unsigned short* __restrict__ V2,
    unsigned short* __restrict__ PA,
    float2* __restrict__ ML2)
{
  constexpr int ITERS = 4096 / NH / 32;
  constexpr int TPK = 128 / NH;               // 32-row tiles per kv slice
  __shared__ __align__(16) char smem[33792];  // 2 x 16KB bufs + 1KB RBUF
  const int tid = threadIdx.x, lane = tid & 63, wid = tid >> 6;   // wid 0..3
  const int rr = lane & 31, hi = lane >> 5;
  // XCD-aware: batch b pinned to XCD pair {2b,2b+1}
  const int p = blockIdx.x;
  const int b = (p & 7) >> 1;
  const int idx = ((p >> 3) << 1) | (p & 1);   // 0..32*NH-1
  const int qst = idx / NH, kvq = idx % NH;    // qst 0..31
  const int q0tile = qst * 4 + wid;            // 32q-tile index 0..127

  // Q fragments (pre-scaled): 8 coalesced 1KB loads
  short8 qf[8];
  {
    const unsigned short* qp = Q2 + (size_t)(b * 128 + q0tile) * 4096 + lane * 8;
#pragma unroll
    for (int kt = 0; kt < 8; ++kt) qf[kt] = *(const short8*)(qp + kt * 512);
  }

  // staging bases for this kv slice
  const unsigned short* kbase = K2 + (size_t)(b * 128 + kvq * TPK) * 4096 + tid * 8;
  const unsigned short* vbase = V2 + (size_t)(b * 128 + kvq * TPK) * 4096 + tid * 8;

  char* const rbuf = smem + 32768 + wid * 128;

  // prologue: stage tile 0 into buf 0
  GLDS16(kbase,        smem + tid * 16);
  GLDS16(kbase + 2048, smem + 4096 + tid * 16);
  GLDS16(vbase,        smem + 8192 + tid * 16);
  GLDS16(vbase + 2048, smem + 12288 + tid * 16);

  f32x16 O[4];
#pragma unroll
  for (int dt = 0; dt < 4; ++dt)
#pragma unroll
    for (int j = 0; j < 16; ++j) O[dt][j] = 0.f;
  f32x16 zc;
#pragma unroll
  for (int j = 0; j < 16; ++j) zc[j] = 0.f;
  float mS = -3.0e38f, lS = 0.f;

  for (int t = 0; t < ITERS; ++t) {
    char* const b0 = smem + (t & 1) * 16384;
    if (t < ITERS - 1) {
      char* const bn = smem + ((t + 1) & 1) * 16384;
      const size_t adv = (size_t)(t + 1) * 4096;
      GLDS16(kbase + adv,        bn + tid * 16);
      GLDS16(kbase + adv + 2048, bn + 4096 + tid * 16);
      GLDS16(vbase + adv,        bn + 8192 + tid * 16);
      GLDS16(vbase + adv + 2048, bn + 12288 + tid * 16);
      asm volatile("s_waitcnt vmcnt(4)" ::: "memory");  // tile-t slices landed
    } else {
      asm volatile("s_waitcnt vmcnt(0)" ::: "memory");
    }
    __builtin_amdgcn_s_barrier();                       // ALL tile-t slices in LDS
    __builtin_amdgcn_sched_barrier(0);

    // ---- QK^T swapped: D[kv=regs][q=lane&31] ----
    f32x16 sT;
    __builtin_amdgcn_s_setprio(1);
    {
      short8 kf[8];
#pragma unroll
      for (int kt = 0; kt < 8; ++kt)
        kf[kt] = *(const short8*)(b0 + kt * 1024 + lane * 16);
      sT = MFMA32(kf[0], qf[0], zc);
#pragma unroll
      for (int kt = 1; kt < 8; ++kt) sT = MFMA32(kf[kt], qf[kt], sT);
    }
    __builtin_amdgcn_s_setprio(0);

    // ---- online softmax over 32 kv; kv row of reg r = (r&3)+8*(r>>2)+4*hi --
    float pm = fmaxf(fmaxf(fmaxf(sT[0], sT[1]), fmaxf(sT[2], sT[3])),
                     fmaxf(fmaxf(sT[4], sT[5]), fmaxf(sT[6], sT[7])));
    pm = fmaxf(pm, fmaxf(fmaxf(fmaxf(sT[8], sT[9]), fmaxf(sT[10], sT[11])),
                         fmaxf(fmaxf(sT[12], sT[13]), fmaxf(sT[14], sT[15]))));
    { i32x2 r = pls(iasi(pm), iasi(pm)); pm = fmaxf(fasf(r[0]), fasf(r[1])); }

    if (!__all(pm - mS <= 8.0f)) {          // defer-max (THR=8)
      float mnew = fmaxf(mS, pm);
      float fsc = fexp2((mS - mnew) * L2E);
      mS = mnew;
      lS *= fsc;
      if (hi == 0) *(float*)(rbuf + rr * 4) = fsc;
      f32x4 fr[4];
#pragma unroll
      for (int i = 0; i < 4; ++i)
        fr[i] = *(const f32x4*)(rbuf + i * 32 + hi * 16);
#pragma unroll
      for (int dt = 0; dt < 4; ++dt)
#pragma unroll
        for (int i = 0; i < 4; ++i)
#pragma unroll
          for (int j = 0; j < 4; ++j) O[dt][i * 4 + j] *= fr[i][j];
    }

    const float mL = mS * L2E;
    float pv[16];
#pragma unroll
    for (int r = 0; r < 16; ++r) pv[r] = fexp2(sT[r] * L2E - mL);
    float s01 = (pv[0] + pv[1]) + (pv[2] + pv[3]);
    float s23 = (pv[4] + pv[5]) + (pv[6] + pv[7]);
    float s45 = (pv[8] + pv[9]) + (pv[10] + pv[11]);
    float s67 = (pv[12] + pv[13]) + (pv[14] + pv[15]);
    float ts = (s01 + s23) + (s45 + s67);
    { i32x2 r = pls(iasi(ts), iasi(ts)); ts = fasf(r[0]) + fasf(r[1]); }
    lS += ts;

    // ---- P -> PV A-fragments fully in registers (T12) ----
    short8 pa0, pa1;
    {
      int dw[8];
#pragma unroll
      for (int m = 0; m < 8; ++m) dw[m] = cvtpk(pv[2 * m], pv[2 * m + 1]);
      i32x2 ra = pls(dw[0], dw[2]);
      i32x2 rb = pls(dw[1], dw[3]);
      i32x2 rc = pls(dw[4], dw[6]);
      i32x2 rd = pls(dw[5], dw[7]);
      i32x4 w0 = {ra[0], rb[0], ra[1], rb[1]};
      i32x4 w1 = {rc[0], rd[0], rc[1], rd[1]};
      pa0 = __builtin_bit_cast(short8, w0);
      pa1 = __builtin_bit_cast(short8, w1);
    }

    // ---- PV: O[q][d] += P[q][kv32] * V[kv32][d] ----
    __builtin_amdgcn_s_setprio(1);
    {
      const char* vb = b0 + 8192;
      short8 vf[4];
#pragma unroll
      for (int dt = 0; dt < 4; ++dt)
        vf[dt] = *(const short8*)(vb + dt * 1024 + lane * 16);
#pragma unroll
      for (int dt = 0; dt < 4; ++dt) O[dt] = MFMA32(pa0, vf[dt], O[dt]);
#pragma unroll
      for (int dt = 0; dt < 4; ++dt)
        vf[dt] = *(const short8*)(vb + 4096 + dt * 1024 + lane * 16);
#pragma unroll
      for (int dt = 0; dt < 4; ++dt) O[dt] = MFMA32(pa1, vf[dt], O[dt]);
    }
    __builtin_amdgcn_s_setprio(0);

    // trailing barrier: all waves done reading b0 -> free for restage at t+1
    __builtin_amdgcn_s_barrier();
  }

  // ---- epilogue: write partial A-frag image + (m,l) ----
  unsigned short* pab = PA + ((size_t)(b * NH + kvq) * 128 + q0tile) * 4096;
#pragma unroll
  for (int dt = 0; dt < 4; ++dt) {
    int kt = dt * 2 + (rr >> 4);
#pragma unroll
    for (int r = 0; r < 16; ++r) {
      int q = (r & 3) + 8 * (r >> 2) + 4 * hi;
      int e = kt * 512 + (((rr >> 3) & 1) * 32 + q) * 8 + (rr & 7);
      pab[e] = f2bf(O[dt][r]);
    }
  }
  if (hi == 0)
    ML2[(size_t)(b * NH + kvq) * 4096 + q0tile * 32 + rr] = make_float2(mS, lS);
}

// ---------------------------------------------------------------------------
// Kernel 3: merge NH KV-slice partials + fused output projection.
// Grid 512, 256 thr = 4 waves; wave w -> out cols [w*32, w*32+32).
// XCD-aware block mapping matches k_attn's producer mapping.
// ---------------------------------------------------------------------------
template <int NH>
__global__ __launch_bounds__(256) void k_merge(
    const unsigned short* __restrict__ PA,
    const float2* __restrict__ ML2,
    const unsigned short* __restrict__ Wo2,
    const float* __restrict__ bo,
    float* __restrict__ out)
{
  const int tid = threadIdx.x, lane = tid & 63, w = tid >> 6;
  const int rr = lane & 31, hi = lane >> 5;
  const int p = blockIdx.x;
  const int b = (p & 7) >> 1;
  const int qt32 = ((p >> 3) << 1) | (p & 1);   // 0..127

  float mh[NH], lh[NH];
#pragma unroll
  for (int h = 0; h < NH; ++h) {
    float2 ml = ML2[(size_t)(b * NH + h) * 4096 + qt32 * 32 + rr];
    mh[h] = ml.x; lh[h] = ml.y;
  }
  float M = mh[0];
#pragma unroll
  for (int h = 1; h < NH; ++h) M = fmaxf(M, mh[h]);
  float ch[NH], L = 0.f;
#pragma unroll
  for (int h = 0; h < NH; ++h) { ch[h] = fexp2((mh[h] - M) * L2E); L += ch[h] * lh[h]; }
  float iL = 1.0f / L;
#pragma unroll
  for (int h = 0; h < NH; ++h) ch[h] *= iL;

  short8 attb[8];
#pragma unroll
  for (int kt = 0; kt < 8; ++kt) {
    float a[8];
#pragma unroll
    for (int j = 0; j < 8; ++j) a[j] = 0.f;
#pragma unroll
    for (int h = 0; h < NH; ++h) {
      short8 ph = *(const short8*)(PA + ((size_t)(b * NH + h) * 128 + qt32) * 4096 +
                                   kt * 512 + lane * 8);
#pragma unroll
      for (int j = 0; j < 8; ++j)
        a[j] += ch[h] * bf2f((unsigned short)ph[j]);
    }
    i32x4 wv = {cvtpk(a[0], a[1]), cvtpk(a[2], a[3]),
                cvtpk(a[4], a[5]), cvtpk(a[6], a[7])};
    attb[kt] = __builtin_bit_cast(short8, wv);
  }

  short8 wof[8];
#pragma unroll
  for (int kt = 0; kt < 8; ++kt)
    wof[kt] = *(const short8*)(Wo2 + (w * 8 + kt) * 512 + lane * 8);

  f32x16 zc;
#pragma unroll
  for (int j = 0; j < 16; ++j) zc[j] = 0.f;
  f32x16 acc = MFMA32(attb[0], wof[0], zc);
#pragma unroll
  for (int kt = 1; kt < 8; ++kt) acc = MFMA32(attb[kt], wof[kt], acc);

  float bov = bo[w * 32 + rr];
  float* op = out + (size_t)(b * 4096 + qt32 * 32) * 128 + w * 32 + rr;
#pragma unroll
  for (int r = 0; r < 16; ++r) {
    int q = (r & 3) + 8 * (r >> 2) + 4 * hi;
    op[q * 128] = acc[r] + bov;
  }
}

// ---------------------------------------------------------------------------
extern "C" void kernel_launch(void* const* d_in, const int* in_sizes, int n_in,
                              void* d_out, int out_size, void* d_ws, size_t ws_size,
                              hipStream_t stream) {
  const float* x  = (const float*)d_in[0];
  const float* Wq = (const float*)d_in[1];
  const float* bq = (const float*)d_in[2];
  const float* Wk = (const float*)d_in[3];
  const float* bk = (const float*)d_in[4];
  const float* Wv = (const float*)d_in[5];
  const float* bv = (const float*)d_in[6];
  const float* Wo = (const float*)d_in[7];
  const float* bo = (const float*)d_in[8];

  const size_t NE = 4u * 4096u * 128u;       // 2M elems per tensor
  unsigned short* Q2  = (unsigned short*)d_ws;
  unsigned short* K2  = Q2 + NE;
  unsigned short* V2  = K2 + NE;
  unsigned short* Wo2 = V2 + NE;             // 16384 elems
  unsigned short* PA  = Wo2 + 16384;

  // ws requirement for NH-way kv split:
  //   (3*NE + 16384 + NH*4*128*4096)*2 bytes  +  NH*4*4096*8 bytes (ML2)
  const size_t paElems8 = (size_t)8 * 4 * 128 * 4096;
  const size_t need8 = (3 * NE + 16384 + paElems8) * 2 + (size_t)8 * 4 * 4096 * 8;

  k_proj<<<768, 256, 0, stream>>>(x, Wq, bq, Wk, bk, Wv, bv, Wo, Q2, K2, V2, Wo2);

  if (ws_size >= need8) {
    float2* ML2 = (float2*)(PA + paElems8);
    k_attn<8><<<1024, 256, 0, stream>>>(Q2, K2, V2, PA, ML2);
    k_merge<8><<<512, 256, 0, stream>>>(PA, ML2, Wo2, bo, (float*)d_out);
  } else {
    const size_t paElems4 = (size_t)4 * 4 * 128 * 4096;
    float2* ML2 = (float2*)(PA + paElems4);
    k_attn<4><<<512, 256, 0, stream>>>(Q2, K2, V2, PA, ML2);
    k_merge<4><<<512, 256, 0, stream>>>(PA, ML2, Wo2, bo, (float*)d_out);
  }
}

// Round 19
// 75.957 us; speedup vs baseline: 1.1796x; 1.1007x over previous
//
#include <hip/hip_runtime.h>
#include <stdint.h>

typedef __attribute__((ext_vector_type(8))) short short8;
typedef __attribute__((ext_vector_type(4))) float f32x4;
typedef __attribute__((ext_vector_type(16))) float f32x16;
typedef __attribute__((ext_vector_type(4))) int i32x4;
typedef __attribute__((ext_vector_type(2))) int i32x2;

#define MFMA16(a, b, c) __builtin_amdgcn_mfma_f32_16x16x32_bf16((a), (b), (c), 0, 0, 0)
#define MFMA32(a, b, c) __builtin_amdgcn_mfma_f32_32x32x16_bf16((a), (b), (c), 0, 0, 0)

typedef __attribute__((address_space(1))) const void GVoid;
typedef __attribute__((address_space(3))) void LVoid;
#define GLDS16(g, l) __builtin_amdgcn_global_load_lds((GVoid*)(g), (LVoid*)(l), 16, 0, 0)

#define L2E 1.4426950408889634f

__device__ __forceinline__ unsigned short f2bf(float f) {
  unsigned int u = __builtin_bit_cast(unsigned int, f);
  u += 0x7fffu + ((u >> 16) & 1u);   // RNE (finite values only)
  return (unsigned short)(u >> 16);
}
__device__ __forceinline__ float bf2f(unsigned short u) {
  return __builtin_bit_cast(float, (unsigned int)u << 16);
}

// raw v_exp_f32: args always <= 0; flush-to-zero is the wanted semantics.
__device__ __forceinline__ float fexp2(float x) {
  return __builtin_amdgcn_exp2f(x);
}

// permlane32_swap via builtin: two simultaneously-live results -> distinct regs
// guaranteed (inline-asm "+v","+v" self-swap was R3's bug).
__device__ __forceinline__ i32x2 pls(int a, int b) {
  return __builtin_amdgcn_permlane32_swap(a, b, false, false);
}
__device__ __forceinline__ float fasf(int x) { return __builtin_bit_cast(float, x); }
__device__ __forceinline__ int iasi(float x) { return __builtin_bit_cast(int, x); }

__device__ __forceinline__ int cvtpk(float lo, float hi) {
  int d;
  asm("v_cvt_pk_bf16_f32 %0, %1, %2" : "=v"(d) : "v"(lo), "v"(hi));
  return d;
}

// ---------------------------------------------------------------------------
// Kernel 1: Q/K/V projections (R15/R16 version, unchanged).
// ---------------------------------------------------------------------------
__global__ __launch_bounds__(256) void k_proj(
    const float* __restrict__ x,
    const float* __restrict__ Wq, const float* __restrict__ bq,
    const float* __restrict__ Wk, const float* __restrict__ bk,
    const float* __restrict__ Wv, const float* __restrict__ bv,
    const float* __restrict__ Wo,
    unsigned short* __restrict__ Q2, unsigned short* __restrict__ K2,
    unsigned short* __restrict__ V2, unsigned short* __restrict__ Wo2)
{
  __shared__ __align__(16) unsigned short wt[128 * 128];  // swizzled W^T, 32KB
  __shared__ __align__(16) unsigned short st[64 * 136];   // store-stage, 17KB
  const int tid  = threadIdx.x;
  const int lane = tid & 63;
  const int wid  = tid >> 6;
  const int l15  = lane & 15;
  const int g    = lane >> 4;
  const int wI   = blockIdx.x >> 8;      // 0=Q, 1=K, 2=V
  const int blk  = blockIdx.x & 255;
  const int r0   = blk * 64 + wid * 16;

  if (blockIdx.x == 0) {
    for (int e = tid; e < 16384; e += 256) {
      int j = e & 7, ln = (e >> 3) & 63, kt = (e >> 9) & 7, dt = e >> 12;
      int h = kt * 16 + (ln >> 5) * 8 + j, oc = dt * 32 + (ln & 31);
      Wo2[e] = f2bf(Wo[h * 128 + oc]);
    }
  }

  short8 af[4];
  {
    const float* xp = x + (r0 + l15) * 128 + g * 8;
#pragma unroll
    for (int kt = 0; kt < 4; ++kt) {
      float4 v0 = *(const float4*)(xp + kt * 32);
      float4 v1 = *(const float4*)(xp + kt * 32 + 4);
      short8 a;
      a[0] = (short)f2bf(v0.x); a[1] = (short)f2bf(v0.y);
      a[2] = (short)f2bf(v0.z); a[3] = (short)f2bf(v0.w);
      a[4] = (short)f2bf(v1.x); a[5] = (short)f2bf(v1.y);
      a[6] = (short)f2bf(v1.z); a[7] = (short)f2bf(v1.w);
      af[kt] = a;
    }
  }

  const float* W  = (wI == 0) ? Wq : (wI == 1) ? Wk : Wv;
  const float* bv_ = (wI == 0) ? bq : (wI == 1) ? bk : bv;

  for (int i = 0; i < 64; ++i) {
    int idx = i * 256 + tid;
    int k = idx >> 7, n = idx & 127;
    int cs = (k >> 3) ^ (n & 7);
    wt[n * 128 + cs * 8 + (k & 7)] = f2bf(W[idx]);
  }
  __syncthreads();

  float bias[8];
#pragma unroll
  for (int nt = 0; nt < 8; ++nt) bias[nt] = bv_[nt * 16 + l15];

  f32x4 acc[8];
#pragma unroll
  for (int nt = 0; nt < 8; ++nt) acc[nt] = (f32x4){0.f, 0.f, 0.f, 0.f};

#pragma unroll
  for (int nt = 0; nt < 8; ++nt) {
    const int n = nt * 16 + l15;
#pragma unroll
    for (int ks = 0; ks < 4; ++ks) {
      int cs = (ks * 4 + g) ^ (n & 7);
      short8 bf = *(const short8*)&wt[n * 128 + cs * 8];
      acc[nt] = MFMA16(af[ks], bf, acc[nt]);
    }
  }

  if (wI < 2) {
    const float sc = (wI == 0) ? 0.08838834764831845f : 1.0f;  // 1/sqrt(128)
#pragma unroll
    for (int nt = 0; nt < 8; ++nt) {
      int col = nt * 16 + l15;
#pragma unroll
      for (int r = 0; r < 4; ++r)
        st[(wid * 16 + g * 4 + r) * 136 + col] = f2bf((acc[nt][r] + bias[nt]) * sc);
    }
    __syncthreads();
    unsigned short* Og = (wI == 0) ? Q2 : K2;
#pragma unroll
    for (int c4 = 0; c4 < 4; ++c4) {
      int c = c4 * 256 + tid;
      int T = c >> 9, cc = c & 511;
      int kt = cc >> 6, hib = (cc >> 5) & 1, s32 = cc & 31;
      int m0 = blk * 64 + T * 32;
      int bb = m0 >> 12, tile = (m0 & 4095) >> 5;
      short8 v = *(const short8*)&st[(T * 32 + s32) * 136 + kt * 16 + hib * 8];
      *(short8*)&Og[(size_t)(bb * 128 + tile) * 4096 + cc * 8] = v;
    }
  } else {
#pragma unroll
    for (int nt = 0; nt < 8; ++nt) {
      int col = nt * 16 + l15;
      int m0 = r0 + g * 4;
      int bb = m0 >> 12, srow = m0 & 4095;
      int idx = (bb * 128 + (srow >> 5)) * 4096 + ((srow >> 4) & 1) * 2048 +
                (col >> 5) * 512 + ((srow >> 3) & 1) * 256 + (col & 31) * 8 +
                (srow & 7);
      ushort4 pk;
      pk.x = f2bf(acc[nt][0] + bias[nt]);
      pk.y = f2bf(acc[nt][1] + bias[nt]);
      pk.z = f2bf(acc[nt][2] + bias[nt]);
      pk.w = f2bf(acc[nt][3] + bias[nt]);
      *(ushort4*)&V2[idx] = pk;
    }
  }
}

// ---------------------------------------------------------------------------
// Kernel 2: flash attention partials (R16 config: KVBLK=64, grid 512, 4 waves,
// 2 blocks/CU, double-buffer, counted vmcnt(8), 2 raw barriers/iter).
// NEW this round: SPLIT SOFTMAX — the two 32-kv subtiles are processed as
// sequential independent online-softmax updates (QK0,QK1 -> SM0 -> PV0 ->
// SM1 -> PV1). SM0 depends only on sT0 (overlaps QK1's MFMAs); SM1 depends
// only on sT1 (overlaps PV0's MFMAs) -> VALU softmax overlaps matrix pipe
// within each wave, breaking the barrier-induced phase serialization.
// ---------------------------------------------------------------------------
__global__ __launch_bounds__(256, 2) void k_attn(
    const unsigned short* __restrict__ Q2,
    const unsigned short* __restrict__ K2,
    const unsigned short* __restrict__ V2,
    unsigned short* __restrict__ PA,
    float2* __restrict__ ML2)
{
  __shared__ __align__(16) char smem[66560];   // 2 x 32KB bufs + 1KB RBUF
  const int tid = threadIdx.x, lane = tid & 63, wid = tid >> 6;   // wid 0..3
  const int rr = lane & 31, hi = lane >> 5;
  // XCD-aware: batch b pinned to XCD pair {2b,2b+1}
  const int p = blockIdx.x;
  const int b = (p & 7) >> 1;
  const int idx = ((p >> 3) << 1) | (p & 1);   // 0..127
  const int qst = idx >> 2, kvq = idx & 3;     // qst 0..31
  const int q0tile = qst * 4 + wid;            // 32q-tile index 0..127

  // Q fragments (pre-scaled): 8 coalesced 1KB loads
  short8 qf[8];
  {
    const unsigned short* qp = Q2 + (size_t)(b * 128 + q0tile) * 4096 + lane * 8;
#pragma unroll
    for (int kt = 0; kt < 8; ++kt) qf[kt] = *(const short8*)(qp + kt * 512);
  }

  // staging sources: thread tid stages 8 x 16B chunks (2 per 8KB tile)
  const unsigned short* gsrc[4];
  gsrc[0] = K2 + (size_t)(b * 128 + kvq * 32 + 0) * 4096 + tid * 8;
  gsrc[1] = K2 + (size_t)(b * 128 + kvq * 32 + 1) * 4096 + tid * 8;
  gsrc[2] = V2 + (size_t)(b * 128 + kvq * 32 + 0) * 4096 + tid * 8;
  gsrc[3] = V2 + (size_t)(b * 128 + kvq * 32 + 1) * 4096 + tid * 8;

  char* const rbuf = smem + 65536 + wid * 128;

  // prologue: stage tile 0 into buf 0
#pragma unroll
  for (int i = 0; i < 4; ++i) {
    GLDS16(gsrc[i], smem + i * 8192 + tid * 16);
    GLDS16(gsrc[i] + 2048, smem + i * 8192 + 4096 + tid * 16);
  }

  f32x16 O[4];
#pragma unroll
  for (int dt = 0; dt < 4; ++dt)
#pragma unroll
    for (int j = 0; j < 16; ++j) O[dt][j] = 0.f;
  f32x16 zc;
#pragma unroll
  for (int j = 0; j < 16; ++j) zc[j] = 0.f;
  float mS = -3.0e38f, lS = 0.f;

  for (int t = 0; t < 16; ++t) {
    char* const b0 = smem + (t & 1) * 32768;
    if (t < 15) {
      char* const bn = smem + ((t + 1) & 1) * 32768;
      const size_t adv = (size_t)(t + 1) * 8192;
#pragma unroll
      for (int i = 0; i < 4; ++i) {
        GLDS16(gsrc[i] + adv, bn + i * 8192 + tid * 16);
        GLDS16(gsrc[i] + adv + 2048, bn + i * 8192 + 4096 + tid * 16);
      }
      asm volatile("s_waitcnt vmcnt(8)" ::: "memory");  // my tile-t slices landed
    } else {
      asm volatile("s_waitcnt vmcnt(0)" ::: "memory");
    }
    __builtin_amdgcn_s_barrier();                       // ALL tile-t slices in LDS
    __builtin_amdgcn_sched_barrier(0);

    // ---- QK^T both 32-kv subtiles (independent chains) ----
    f32x16 sT0, sT1;
    __builtin_amdgcn_s_setprio(1);
    {
      short8 kf[8];
#pragma unroll
      for (int kt = 0; kt < 8; ++kt)
        kf[kt] = *(const short8*)(b0 + kt * 1024 + lane * 16);
      sT0 = MFMA32(kf[0], qf[0], zc);
#pragma unroll
      for (int kt = 1; kt < 8; ++kt) sT0 = MFMA32(kf[kt], qf[kt], sT0);
    }
    {
      short8 kf[8];
#pragma unroll
      for (int kt = 0; kt < 8; ++kt)
        kf[kt] = *(const short8*)(b0 + 8192 + kt * 1024 + lane * 16);
      sT1 = MFMA32(kf[0], qf[0], zc);
#pragma unroll
      for (int kt = 1; kt < 8; ++kt) sT1 = MFMA32(kf[kt], qf[kt], sT1);
    }
    __builtin_amdgcn_s_setprio(0);

    // ================= half 0: SM0 (overlaps QK1 in flight) ================
    {
      float pm = fmaxf(fmaxf(fmaxf(sT0[0], sT0[1]), fmaxf(sT0[2], sT0[3])),
                       fmaxf(fmaxf(sT0[4], sT0[5]), fmaxf(sT0[6], sT0[7])));
      pm = fmaxf(pm, fmaxf(fmaxf(fmaxf(sT0[8], sT0[9]), fmaxf(sT0[10], sT0[11])),
                           fmaxf(fmaxf(sT0[12], sT0[13]), fmaxf(sT0[14], sT0[15]))));
      { i32x2 r = pls(iasi(pm), iasi(pm)); pm = fmaxf(fasf(r[0]), fasf(r[1])); }

      if (!__all(pm - mS <= 8.0f)) {          // defer-max (THR=8)
        float mnew = fmaxf(mS, pm);
        float fsc = fexp2((mS - mnew) * L2E);
        mS = mnew;
        lS *= fsc;
        if (hi == 0) *(float*)(rbuf + rr * 4) = fsc;
        f32x4 fr[4];
#pragma unroll
        for (int i = 0; i < 4; ++i)
          fr[i] = *(const f32x4*)(rbuf + i * 32 + hi * 16);
#pragma unroll
        for (int dt = 0; dt < 4; ++dt)
#pragma unroll
          for (int i = 0; i < 4; ++i)
#pragma unroll
            for (int j = 0; j < 4; ++j) O[dt][i * 4 + j] *= fr[i][j];
      }

      const float mL = mS * L2E;
      float pv[16];
#pragma unroll
      for (int r = 0; r < 16; ++r) pv[r] = fexp2(sT0[r] * L2E - mL);
      float s01 = (pv[0] + pv[1]) + (pv[2] + pv[3]);
      float s23 = (pv[4] + pv[5]) + (pv[6] + pv[7]);
      float s45 = (pv[8] + pv[9]) + (pv[10] + pv[11]);
      float s67 = (pv[12] + pv[13]) + (pv[14] + pv[15]);
      float ts = (s01 + s23) + (s45 + s67);
      { i32x2 r = pls(iasi(ts), iasi(ts)); ts = fasf(r[0]) + fasf(r[1]); }
      lS += ts;

      short8 pa0, pa1;
      {
        int dw[8];
#pragma unroll
        for (int m = 0; m < 8; ++m) dw[m] = cvtpk(pv[2 * m], pv[2 * m + 1]);
        i32x2 ra = pls(dw[0], dw[2]);
        i32x2 rb = pls(dw[1], dw[3]);
        i32x2 rc = pls(dw[4], dw[6]);
        i32x2 rd = pls(dw[5], dw[7]);
        i32x4 w0 = {ra[0], rb[0], ra[1], rb[1]};
        i32x4 w1 = {rc[0], rd[0], rc[1], rd[1]};
        pa0 = __builtin_bit_cast(short8, w0);
        pa1 = __builtin_bit_cast(short8, w1);
      }

      // ---- PV half 0 (V subtile 0: ks = 0,1) ----
      __builtin_amdgcn_s_setprio(1);
      {
        const char* vb = b0 + 16384;
        short8 vf[4];
#pragma unroll
        for (int dt = 0; dt < 4; ++dt)
          vf[dt] = *(const short8*)(vb + dt * 1024 + lane * 16);
#pragma unroll
        for (int dt = 0; dt < 4; ++dt) O[dt] = MFMA32(pa0, vf[dt], O[dt]);
#pragma unroll
        for (int dt = 0; dt < 4; ++dt)
          vf[dt] = *(const short8*)(vb + 4096 + dt * 1024 + lane * 16);
#pragma unroll
        for (int dt = 0; dt < 4; ++dt) O[dt] = MFMA32(pa1, vf[dt], O[dt]);
      }
      __builtin_amdgcn_s_setprio(0);
    }

    // ================= half 1: SM1 (overlaps PV0 in flight) ================
    {
      float pm = fmaxf(fmaxf(fmaxf(sT1[0], sT1[1]), fmaxf(sT1[2], sT1[3])),
                       fmaxf(fmaxf(sT1[4], sT1[5]), fmaxf(sT1[6], sT1[7])));
      pm = fmaxf(pm, fmaxf(fmaxf(fmaxf(sT1[8], sT1[9]), fmaxf(sT1[10], sT1[11])),
                           fmaxf(fmaxf(sT1[12], sT1[13]), fmaxf(sT1[14], sT1[15]))));
      { i32x2 r = pls(iasi(pm), iasi(pm)); pm = fmaxf(fasf(r[0]), fasf(r[1])); }

      if (!__all(pm - mS <= 8.0f)) {          // defer-max (THR=8)
        float mnew = fmaxf(mS, pm);
        float fsc = fexp2((mS - mnew) * L2E);
        mS = mnew;
        lS *= fsc;
        if (hi == 0) *(float*)(rbuf + rr * 4) = fsc;
        f32x4 fr[4];
#pragma unroll
        for (int i = 0; i < 4; ++i)
          fr[i] = *(const f32x4*)(rbuf + i * 32 + hi * 16);
#pragma unroll
        for (int dt = 0; dt < 4; ++dt)
#pragma unroll
          for (int i = 0; i < 4; ++i)
#pragma unroll
            for (int j = 0; j < 4; ++j) O[dt][i * 4 + j] *= fr[i][j];
      }

      const float mL = mS * L2E;
      float pv[16];
#pragma unroll
      for (int r = 0; r < 16; ++r) pv[r] = fexp2(sT1[r] * L2E - mL);
      float s01 = (pv[0] + pv[1]) + (pv[2] + pv[3]);
      float s23 = (pv[4] + pv[5]) + (pv[6] + pv[7]);
      float s45 = (pv[8] + pv[9]) + (pv[10] + pv[11]);
      float s67 = (pv[12] + pv[13]) + (pv[14] + pv[15]);
      float ts = (s01 + s23) + (s45 + s67);
      { i32x2 r = pls(iasi(ts), iasi(ts)); ts = fasf(r[0]) + fasf(r[1]); }
      lS += ts;

      short8 pa2, pa3;
      {
        int dw[8];
#pragma unroll
        for (int m = 0; m < 8; ++m) dw[m] = cvtpk(pv[2 * m], pv[2 * m + 1]);
        i32x2 ra = pls(dw[0], dw[2]);
        i32x2 rb = pls(dw[1], dw[3]);
        i32x2 rc = pls(dw[4], dw[6]);
        i32x2 rd = pls(dw[5], dw[7]);
        i32x4 w0 = {ra[0], rb[0], ra[1], rb[1]};
        i32x4 w1 = {rc[0], rd[0], rc[1], rd[1]};
        pa2 = __builtin_bit_cast(short8, w0);
        pa3 = __builtin_bit_cast(short8, w1);
      }

      // ---- PV half 1 (V subtile 1: ks = 2,3) ----
      __builtin_amdgcn_s_setprio(1);
      {
        const char* vb = b0 + 16384 + 8192;
        short8 vf[4];
#pragma unroll
        for (int dt = 0; dt < 4; ++dt)
          vf[dt] = *(const short8*)(vb + dt * 1024 + lane * 16);
#pragma unroll
        for (int dt = 0; dt < 4; ++dt) O[dt] = MFMA32(pa2, vf[dt], O[dt]);
#pragma unroll
        for (int dt = 0; dt < 4; ++dt)
          vf[dt] = *(const short8*)(vb + 4096 + dt * 1024 + lane * 16);
#pragma unroll
        for (int dt = 0; dt < 4; ++dt) O[dt] = MFMA32(pa3, vf[dt], O[dt]);
      }
      __builtin_amdgcn_s_setprio(0);
    }

    // trailing barrier: all waves done reading b0 -> free for restage at t+1
    __builtin_amdgcn_s_barrier();
  }

  // ---- epilogue: write partial A-frag image + (m,l) ----
  unsigned short* pab = PA + ((size_t)(b * 4 + kvq) * 128 + q0tile) * 4096;
#pragma unroll
  for (int dt = 0; dt < 4; ++dt) {
    int kt = dt * 2 + (rr >> 4);
#pragma unroll
    for (int r = 0; r < 16; ++r) {
      int q = (r & 3) + 8 * (r >> 2) + 4 * hi;
      int e = kt * 512 + (((rr >> 3) & 1) * 32 + q) * 8 + (rr & 7);
      pab[e] = f2bf(O[dt][r]);
    }
  }
  if (hi == 0)
    ML2[(size_t)(b * 4 + kvq) * 4096 + q0tile * 32 + rr] = make_float2(mS, lS);
}

// ---------------------------------------------------------------------------
// Kernel 3: merge 4 KV-quarter partials + fused output projection
// (R16 version, XCD-aware mapping matches k_attn's producers).
// ---------------------------------------------------------------------------
__global__ __launch_bounds__(256) void k_merge(
    const unsigned short* __restrict__ PA,
    const float2* __restrict__ ML2,
    const unsigned short* __restrict__ Wo2,
    const float* __restrict__ bo,
    float* __restrict__ out)
{
  const int tid = threadIdx.x, lane = tid & 63, w = tid >> 6;
  const int rr = lane & 31, hi = lane >> 5;
  const int p = blockIdx.x;
  const int b = (p & 7) >> 1;
  const int qt32 = ((p >> 3) << 1) | (p & 1);   // 0..127

  float mh[4], lh[4];
#pragma unroll
  for (int h = 0; h < 4; ++h) {
    float2 ml = ML2[(size_t)(b * 4 + h) * 4096 + qt32 * 32 + rr];
    mh[h] = ml.x; lh[h] = ml.y;
  }
  float M = fmaxf(fmaxf(mh[0], mh[1]), fmaxf(mh[2], mh[3]));
  float ch[4], L = 0.f;
#pragma unroll
  for (int h = 0; h < 4; ++h) { ch[h] = fexp2((mh[h] - M) * L2E); L += ch[h] * lh[h]; }
  float iL = 1.0f / L;
#pragma unroll
  for (int h = 0; h < 4; ++h) ch[h] *= iL;

  short8 attb[8];
#pragma unroll
  for (int kt = 0; kt < 8; ++kt) {
    float a[8];
#pragma unroll
    for (int j = 0; j < 8; ++j) a[j] = 0.f;
#pragma unroll
    for (int h = 0; h < 4; ++h) {
      short8 ph = *(const short8*)(PA + ((size_t)(b * 4 + h) * 128 + qt32) * 4096 +
                                   kt * 512 + lane * 8);
#pragma unroll
      for (int j = 0; j < 8; ++j)
        a[j] += ch[h] * bf2f((unsigned short)ph[j]);
    }
    i32x4 wv = {cvtpk(a[0], a[1]), cvtpk(a[2], a[3]),
                cvtpk(a[4], a[5]), cvtpk(a[6], a[7])};
    attb[kt] = __builtin_bit_cast(short8, wv);
  }

  short8 wof[8];
#pragma unroll
  for (int kt = 0; kt < 8; ++kt)
    wof[kt] = *(const short8*)(Wo2 + (w * 8 + kt) * 512 + lane * 8);

  f32x16 zc;
#pragma unroll
  for (int j = 0; j < 16; ++j) zc[j] = 0.f;
  f32x16 acc = MFMA32(attb[0], wof[0], zc);
#pragma unroll
  for (int kt = 1; kt < 8; ++kt) acc = MFMA32(attb[kt], wof[kt], acc);

  float bov = bo[w * 32 + rr];
  float* op = out + (size_t)(b * 4096 + qt32 * 32) * 128 + w * 32 + rr;
#pragma unroll
  for (int r = 0; r < 16; ++r) {
    int q = (r & 3) + 8 * (r >> 2) + 4 * hi;
    op[q * 128] = acc[r] + bov;
  }
}

// ---------------------------------------------------------------------------
extern "C" void kernel_launch(void* const* d_in, const int* in_sizes, int n_in,
                              void* d_out, int out_size, void* d_ws, size_t ws_size,
                              hipStream_t stream) {
  const float* x  = (const float*)d_in[0];
  const float* Wq = (const float*)d_in[1];
  const float* bq = (const float*)d_in[2];
  const float* Wk = (const float*)d_in[3];
  const float* bk = (const float*)d_in[4];
  const float* Wv = (const float*)d_in[5];
  const float* bv = (const float*)d_in[6];
  const float* Wo = (const float*)d_in[7];
  const float* bo = (const float*)d_in[8];

  const size_t NE = 4u * 4096u * 128u;       // 2M elems per tensor
  unsigned short* Q2  = (unsigned short*)d_ws;
  unsigned short* K2  = Q2 + NE;
  unsigned short* V2  = K2 + NE;
  unsigned short* Wo2 = V2 + NE;             // 16384 elems
  unsigned short* PA  = Wo2 + 16384;         // 16 * 128 * 4096 = 8M elems
  float2*         ML2 = (float2*)(PA + (size_t)16 * 128 * 4096);  // 64K float2

  k_proj<<<768, 256, 0, stream>>>(x, Wq, bq, Wk, bk, Wv, bv, Wo, Q2, K2, V2, Wo2);
  k_attn<<<512, 256, 0, stream>>>(Q2, K2, V2, PA, ML2);
  k_merge<<<512, 256, 0, stream>>>(PA, ML2, Wo2, bo, (float*)d_out);
}